// Round 5
// baseline (2675.114 us; speedup 1.0000x reference)
//
#include <hip/hip_runtime.h>

#define N_NODES 50000
#define C1 64    // in channels
#define C2 128   // hidden
#define C3 64    // latent / out
#define NBUCK ((N_NODES + 63) / 64)   // 782 coarse buckets of 64 dst nodes

// ---------------- zero indeg + bucket counts + stats ----------------
__global__ void k_zero(int* __restrict__ indeg, int* __restrict__ bcount,
                       float* __restrict__ stats) {
    int i = blockIdx.x * blockDim.x + threadIdx.x;
    if (i < N_NODES) indeg[i] = 0;
    if (i < NBUCK) bcount[i] = 0;
    if (i < 512) stats[i] = 0.0f;
}

// ---------------- fused: per-node indegree + coarse bucket histogram ----------------
__global__ __launch_bounds__(256) void k_hist(const int* __restrict__ dst, int E,
                                              int* __restrict__ indeg,
                                              int* __restrict__ bcount) {
    __shared__ int lh[NBUCK];
    int tid = threadIdx.x;
    for (int i = tid; i < NBUCK; i += 256) lh[i] = 0;
    __syncthreads();
    int stride = gridDim.x * blockDim.x;
    for (int e = blockIdx.x * blockDim.x + tid; e < E; e += stride) {
        int d = dst[e];
        atomicAdd(&indeg[d], 1);
        atomicAdd(&lh[d >> 6], 1);
    }
    __syncthreads();
    for (int i = tid; i < NBUCK; i += 256)
        if (lh[i]) atomicAdd(&bcount[i], lh[i]);
}

// ---------------- scan 782 bucket counts (single block) ----------------
__global__ __launch_bounds__(1024) void k_scanb(const int* __restrict__ bcount,
                                                int* __restrict__ bstart,
                                                int* __restrict__ bcursor) {
    __shared__ int sums[1024];
    int t = threadIdx.x;
    int v = (t < NBUCK) ? bcount[t] : 0;
    sums[t] = v;
    __syncthreads();
    for (int off = 1; off < 1024; off <<= 1) {
        int u = (t >= off) ? sums[t - off] : 0;
        __syncthreads();
        sums[t] += u;
        __syncthreads();
    }
    if (t < NBUCK) {
        int ex = sums[t] - v;
        bstart[t] = ex;
        bcursor[t] = ex;
    }
}

// ---------------- dinv ----------------
__global__ void k_dinv(const int* __restrict__ indeg, float* __restrict__ dinv) {
    int i = blockIdx.x * blockDim.x + threadIdx.x;
    if (i < N_NODES) dinv[i] = rsqrtf(1.0f + (float)indeg[i]);
}

// ---------------- coarse scatter: pack (src<<6 | dst&63) into bucket segments ----------------
__global__ void k_scatterc(const int* __restrict__ src, const int* __restrict__ dst, int E,
                           int* __restrict__ bcursor, int* __restrict__ pairs) {
    int e = blockIdx.x * blockDim.x + threadIdx.x;
    if (e < E) {
        int d = dst[e];
        int pos = atomicAdd(&bcursor[d >> 6], 1);
        pairs[pos] = (src[e] << 6) | (d & 63);
    }
}

// ---------------- GEMM1: h1 = x @ W1 ----------------
__global__ __launch_bounds__(256) void k_gemm1(const float* __restrict__ x,
                                               const float* __restrict__ W1,
                                               float* __restrict__ h1) {
    __shared__ float Ws[C1 * C2];   // 32 KB
    __shared__ float Xs[32 * C1];   //  8 KB
    int tid = threadIdx.x;
    int r0 = blockIdx.x * 32;
    for (int i = tid; i < C1 * C2; i += 256) Ws[i] = W1[i];
    for (int i = tid; i < 32 * C1; i += 256) {
        int row = r0 + (i >> 6);
        Xs[i] = (row < N_NODES) ? x[row * C1 + (i & 63)] : 0.0f;
    }
    __syncthreads();
    int c = tid & 127;
    int rg = tid >> 7;
    float acc[16];
#pragma unroll
    for (int r = 0; r < 16; ++r) acc[r] = 0.0f;
    for (int k = 0; k < C1; ++k) {
        float w = Ws[k * C2 + c];
#pragma unroll
        for (int r = 0; r < 16; ++r)
            acc[r] = fmaf(Xs[(rg * 16 + r) * C1 + k], w, acc[r]);
    }
#pragma unroll
    for (int r = 0; r < 16; ++r) {
        int row = r0 + rg * 16 + r;
        if (row < N_NODES) h1[row * C2 + c] = acc[r];
    }
}

// ---------------- pull layer 1: block-per-bucket, LDS accumulators ----------------
__global__ __launch_bounds__(256) void k_pull1(const int* __restrict__ bstart,
                                               const int* __restrict__ bcount,
                                               const int* __restrict__ pairs,
                                               const float* __restrict__ h1,
                                               const float* __restrict__ dinv,
                                               const float* __restrict__ b1,
                                               float* __restrict__ agg1) {
    __shared__ float accx[64][64];   // 16 KB: even channels (ch = 2*lane)
    __shared__ float accy[64][64];   // 16 KB: odd channels  (ch = 2*lane+1)
    __shared__ float sdinv[64];
    __shared__ int   lsd[256];
    __shared__ float lsw[256];
    int b = blockIdx.x;
    int tid = threadIdx.x, wid = tid >> 6, lane = tid & 63;
    int node0 = b * 64;
    if (tid < 64) {
        int nd = node0 + tid;
        sdinv[tid] = (nd < N_NODES) ? dinv[nd] : 0.0f;
    }
    __syncthreads();
    // init: self-loop + bias
    float2 bb = *(const float2*)(b1 + lane * 2);
#pragma unroll 4
    for (int r = 0; r < 16; ++r) {
        int lr = wid * 16 + r;
        int nd = node0 + lr;
        if (nd < N_NODES) {
            float dd = sdinv[lr];
            float2 h = *(const float2*)(h1 + nd * C2 + lane * 2);
            accx[lr][lane] = fmaf(h.x, dd * dd, bb.x);
            accy[lr][lane] = fmaf(h.y, dd * dd, bb.y);
        }
    }
    __syncthreads();
    // edges, split across 4 waves
    int estart = bstart[b], ecnt = bcount[b];
    int w0 = estart + (ecnt * wid) / 4;
    int w1 = estart + (ecnt * (wid + 1)) / 4;
    for (int j0 = w0; j0 < w1; j0 += 64) {
        int n = w1 - j0; if (n > 64) n = 64;
        if (lane < n) {
            int pk = pairs[j0 + lane];
            lsd[wid * 64 + lane] = pk;
            lsw[wid * 64 + lane] = dinv[pk >> 6] * sdinv[pk & 63];
        }
        for (int k = 0; k < n; ++k) {
            int pk2 = lsd[wid * 64 + k];
            float w2 = lsw[wid * 64 + k];
            int s2 = pk2 >> 6, dl2 = pk2 & 63;
            float2 v = *(const float2*)(h1 + s2 * C2 + lane * 2);
            atomicAdd(&accx[dl2][lane], v.x * w2);
            atomicAdd(&accy[dl2][lane], v.y * w2);
        }
    }
    __syncthreads();
#pragma unroll 4
    for (int r = 0; r < 16; ++r) {
        int lr = wid * 16 + r;
        int nd = node0 + lr;
        if (nd < N_NODES) {
            float2 o; o.x = accx[lr][lane]; o.y = accy[lr][lane];
            *(float2*)(agg1 + nd * C2 + lane * 2) = o;
        }
    }
}

// ---------------- BN stats ----------------
__global__ __launch_bounds__(256) void k_stats(const float* __restrict__ agg1,
                                               float* __restrict__ stats) {
    __shared__ float ls[256], lq[256];
    int tid = threadIdx.x;
    int c = tid & 127, half = tid >> 7;
    float s = 0.0f, q = 0.0f;
    for (int row = blockIdx.x * 2 + half; row < N_NODES; row += gridDim.x * 2) {
        float v = agg1[row * C2 + c];
        s += v; q += v * v;
    }
    ls[tid] = s; lq[tid] = q;
    __syncthreads();
    if (tid < 128) {
        s = ls[tid] + ls[tid + 128];
        q = lq[tid] + lq[tid + 128];
        unsafeAtomicAdd(&stats[c], s);
        unsafeAtomicAdd(&stats[128 + c], q);
    }
}

__global__ void k_bnparam(const float* __restrict__ gamma, const float* __restrict__ beta,
                          float* __restrict__ stats) {
    int c = threadIdx.x;
    if (c < 128) {
        const float invN = 1.0f / (float)N_NODES;
        float mean = stats[c] * invN;
        float var = stats[128 + c] * invN - mean * mean;
        float sc = gamma[c] * rsqrtf(var + 1e-5f);
        stats[256 + c] = sc;
        stats[384 + c] = beta[c] - mean * sc;
    }
}

// ---------------- GEMM2: h2 = relu(bn(agg1)) @ W2 ----------------
__global__ __launch_bounds__(256) void k_gemm2(const float* __restrict__ agg1,
                                               const float* __restrict__ W2,
                                               const float* __restrict__ stats,
                                               float* __restrict__ h2) {
    __shared__ float Ws[C2 * C3];   // 32 KB
    __shared__ float As[32 * C2];   // 16 KB
    int tid = threadIdx.x;
    int r0 = blockIdx.x * 32;
    for (int i = tid; i < C2 * C3; i += 256) Ws[i] = W2[i];
    for (int i = tid; i < 32 * C2; i += 256) {
        int row = r0 + (i >> 7);
        int cc = i & 127;
        float v = 0.0f;
        if (row < N_NODES)
            v = fmaxf(fmaf(agg1[row * C2 + cc], stats[256 + cc], stats[384 + cc]), 0.0f);
        As[i] = v;
    }
    __syncthreads();
    int c = tid & 63;
    int rg = tid >> 6;
    float acc[8];
#pragma unroll
    for (int r = 0; r < 8; ++r) acc[r] = 0.0f;
    for (int k = 0; k < C2; ++k) {
        float w = Ws[k * C3 + c];
#pragma unroll
        for (int r = 0; r < 8; ++r)
            acc[r] = fmaf(As[(rg * 8 + r) * C2 + k], w, acc[r]);
    }
#pragma unroll
    for (int r = 0; r < 8; ++r) {
        int row = r0 + rg * 8 + r;
        if (row < N_NODES) h2[row * C3 + c] = acc[r];
    }
}

// ---------------- pull layer 2: block-per-bucket, LDS accumulator ----------------
__global__ __launch_bounds__(256) void k_pull2(const int* __restrict__ bstart,
                                               const int* __restrict__ bcount,
                                               const int* __restrict__ pairs,
                                               const float* __restrict__ h2,
                                               const float* __restrict__ dinv,
                                               const float* __restrict__ b2,
                                               float* __restrict__ out) {
    __shared__ float acc[64][64];    // 16 KB: ch = lane
    __shared__ float sdinv[64];
    __shared__ int   lsd[256];
    __shared__ float lsw[256];
    int b = blockIdx.x;
    int tid = threadIdx.x, wid = tid >> 6, lane = tid & 63;
    int node0 = b * 64;
    if (tid < 64) {
        int nd = node0 + tid;
        sdinv[tid] = (nd < N_NODES) ? dinv[nd] : 0.0f;
    }
    __syncthreads();
    float bv = b2[lane];
#pragma unroll 4
    for (int r = 0; r < 16; ++r) {
        int lr = wid * 16 + r;
        int nd = node0 + lr;
        if (nd < N_NODES) {
            float dd = sdinv[lr];
            acc[lr][lane] = fmaf(h2[nd * C3 + lane], dd * dd, bv);
        }
    }
    __syncthreads();
    int estart = bstart[b], ecnt = bcount[b];
    int w0 = estart + (ecnt * wid) / 4;
    int w1 = estart + (ecnt * (wid + 1)) / 4;
    for (int j0 = w0; j0 < w1; j0 += 64) {
        int n = w1 - j0; if (n > 64) n = 64;
        if (lane < n) {
            int pk = pairs[j0 + lane];
            lsd[wid * 64 + lane] = pk;
            lsw[wid * 64 + lane] = dinv[pk >> 6] * sdinv[pk & 63];
        }
        for (int k = 0; k < n; ++k) {
            int pk2 = lsd[wid * 64 + k];
            float w2 = lsw[wid * 64 + k];
            int s2 = pk2 >> 6, dl2 = pk2 & 63;
            atomicAdd(&acc[dl2][lane], h2[s2 * C3 + lane] * w2);
        }
    }
    __syncthreads();
#pragma unroll 4
    for (int r = 0; r < 16; ++r) {
        int lr = wid * 16 + r;
        int nd = node0 + lr;
        if (nd < N_NODES) out[nd * C3 + lane] = acc[lr][lane];
    }
}

extern "C" void kernel_launch(void* const* d_in, const int* in_sizes, int n_in,
                              void* d_out, int out_size, void* d_ws, size_t ws_size,
                              hipStream_t stream) {
    const float* x     = (const float*)d_in[0];
    const int*   ei    = (const int*)d_in[1];
    const float* W1    = (const float*)d_in[2];
    const float* b1    = (const float*)d_in[3];
    const float* gamma = (const float*)d_in[4];
    const float* beta  = (const float*)d_in[5];
    const float* W2    = (const float*)d_in[6];
    const float* b2    = (const float*)d_in[7];
    float* out = (float*)d_out;

    int E = in_sizes[1] / 2;
    const int* src = ei;
    const int* dst = ei + E;

    // workspace layout (bytes):
    //   0         dinv     [50176 f]   200704
    //   200704    stats    [512 f]     2048
    //   202752    indeg    [50176 i]   200704
    //   403456    bcount   [1024 i]    4096
    //   407552    bstart   [1024 i]    4096
    //   411648    bcursor  [1024 i]    4096
    //   415744    pairs    [1.6M i]    6400000
    //   6815744   h1/h2    [50000*128] 25600000
    //   32415744  agg1     [50000*128] 25600000  -> end 58015744
    char* ws = (char*)d_ws;
    float* dinv    = (float*)ws;
    float* stats   = (float*)(ws + 200704);
    int*   indeg   = (int*)(ws + 202752);
    int*   bcount  = (int*)(ws + 403456);
    int*   bstart  = (int*)(ws + 407552);
    int*   bcursor = (int*)(ws + 411648);
    int*   pairs   = (int*)(ws + 415744);
    float* h1      = (float*)(ws + 6815744);
    float* agg1    = (float*)(ws + 32415744);
    float* h2      = h1;   // h1 dead after k_pull1

    const int nblk_nodes = (N_NODES + 255) / 256;
    const int nblk_rows  = (N_NODES + 31) / 32;
    const int nblk_edge  = (E + 255) / 256;

    k_zero<<<nblk_nodes, 256, 0, stream>>>(indeg, bcount, stats);
    k_hist<<<256, 256, 0, stream>>>(dst, E, indeg, bcount);
    k_scanb<<<1, 1024, 0, stream>>>(bcount, bstart, bcursor);
    k_dinv<<<nblk_nodes, 256, 0, stream>>>(indeg, dinv);
    k_scatterc<<<nblk_edge, 256, 0, stream>>>(src, dst, E, bcursor, pairs);

    k_gemm1<<<nblk_rows, 256, 0, stream>>>(x, W1, h1);
    k_pull1<<<NBUCK, 256, 0, stream>>>(bstart, bcount, pairs, h1, dinv, b1, agg1);

    k_stats<<<256, 256, 0, stream>>>(agg1, stats);
    k_bnparam<<<1, 128, 0, stream>>>(gamma, beta, stats);

    k_gemm2<<<nblk_rows, 256, 0, stream>>>(agg1, W2, stats, h2);
    k_pull2<<<NBUCK, 256, 0, stream>>>(bstart, bcount, pairs, h2, dinv, b2, out);
}

// Round 6
// 846.051 us; speedup vs baseline: 3.1619x; 3.1619x over previous
//
#include <hip/hip_runtime.h>

#define N_NODES 50000
#define C1 64    // in channels
#define C2 128   // hidden
#define C3 64    // latent / out
#define NBUCK ((N_NODES + 63) / 64)   // 782 coarse buckets of 64 dst nodes
#define BCAP 8192                     // max edges per bucket (mean 2046, sigma 45 -> 136 sigma)

// ---------------- zero indeg + bucket counts + stats ----------------
__global__ void k_zero(int* __restrict__ indeg, int* __restrict__ bcount,
                       float* __restrict__ stats) {
    int i = blockIdx.x * blockDim.x + threadIdx.x;
    if (i < N_NODES) indeg[i] = 0;
    if (i < NBUCK) bcount[i] = 0;
    if (i < 512) stats[i] = 0.0f;
}

// ---------------- fused: per-node indegree + coarse bucket histogram ----------------
__global__ __launch_bounds__(256) void k_hist(const int* __restrict__ dst, int E,
                                              int* __restrict__ indeg,
                                              int* __restrict__ bcount) {
    __shared__ int lh[NBUCK];
    int tid = threadIdx.x;
    for (int i = tid; i < NBUCK; i += 256) lh[i] = 0;
    __syncthreads();
    int stride = gridDim.x * blockDim.x;
    for (int e = blockIdx.x * blockDim.x + tid; e < E; e += stride) {
        int d = dst[e];
        atomicAdd(&indeg[d], 1);
        atomicAdd(&lh[d >> 6], 1);
    }
    __syncthreads();
    for (int i = tid; i < NBUCK; i += 256)
        if (lh[i]) atomicAdd(&bcount[i], lh[i]);
}

// ---------------- scan 782 bucket counts (single block) ----------------
__global__ __launch_bounds__(1024) void k_scanb(const int* __restrict__ bcount,
                                                int* __restrict__ bstart,
                                                int* __restrict__ bcursor) {
    __shared__ int sums[1024];
    int t = threadIdx.x;
    int v = (t < NBUCK) ? bcount[t] : 0;
    sums[t] = v;
    __syncthreads();
    for (int off = 1; off < 1024; off <<= 1) {
        int u = (t >= off) ? sums[t - off] : 0;
        __syncthreads();
        sums[t] += u;
        __syncthreads();
    }
    if (t < NBUCK) {
        int ex = sums[t] - v;
        bstart[t] = ex;
        bcursor[t] = ex;
    }
}

// ---------------- dinv ----------------
__global__ void k_dinv(const int* __restrict__ indeg, float* __restrict__ dinv) {
    int i = blockIdx.x * blockDim.x + threadIdx.x;
    if (i < N_NODES) dinv[i] = rsqrtf(1.0f + (float)indeg[i]);
}

// ---------------- coarse scatter: pack (src<<6 | dst&63) into bucket segments ----------------
__global__ void k_scatterc(const int* __restrict__ src, const int* __restrict__ dst, int E,
                           int* __restrict__ bcursor, int* __restrict__ pairs) {
    int e = blockIdx.x * blockDim.x + threadIdx.x;
    if (e < E) {
        int d = dst[e];
        int pos = atomicAdd(&bcursor[d >> 6], 1);
        pairs[pos] = (src[e] << 6) | (d & 63);
    }
}

// ---------------- refine: in-place, bucket -> node-major CSR (+rowstart) ----------------
__global__ __launch_bounds__(256) void k_refine(const int* __restrict__ bstart,
                                                const int* __restrict__ bcount,
                                                const int* __restrict__ indeg,
                                                int* __restrict__ rowstart,
                                                int* __restrict__ pairs) {
    __shared__ int stage[BCAP];   // 32 KB
    __shared__ int lcur[64];
    int b = blockIdx.x;
    int tid = threadIdx.x;
    int e0 = bstart[b], n = bcount[b];
    if (tid < 64) {   // wave 0: shfl-scan the 64 node degrees
        int nd = b * 64 + tid;
        int dg = (nd < N_NODES) ? indeg[nd] : 0;
        int pfx = dg;
#pragma unroll
        for (int off = 1; off < 64; off <<= 1) {
            int v = __shfl_up(pfx, off);
            if (tid >= off) pfx += v;
        }
        int st = e0 + (pfx - dg);   // exclusive
        if (nd < N_NODES) rowstart[nd] = st;
        lcur[tid] = st;
    }
    for (int j = tid; j < n; j += 256) stage[j] = pairs[e0 + j];
    __syncthreads();
    for (int j = tid; j < n; j += 256) {
        int pk = stage[j];
        int pos = atomicAdd(&lcur[pk & 63], 1);
        pairs[pos] = pk >> 6;   // store src only, node-major
    }
}

// ---------------- GEMM1: h1 = x @ W1 ----------------
__global__ __launch_bounds__(256) void k_gemm1(const float* __restrict__ x,
                                               const float* __restrict__ W1,
                                               float* __restrict__ h1) {
    __shared__ float Ws[C1 * C2];   // 32 KB
    __shared__ float Xs[32 * C1];   //  8 KB
    int tid = threadIdx.x;
    int r0 = blockIdx.x * 32;
    for (int i = tid; i < C1 * C2; i += 256) Ws[i] = W1[i];
    for (int i = tid; i < 32 * C1; i += 256) {
        int row = r0 + (i >> 6);
        Xs[i] = (row < N_NODES) ? x[row * C1 + (i & 63)] : 0.0f;
    }
    __syncthreads();
    int c = tid & 127;
    int rg = tid >> 7;
    float acc[16];
#pragma unroll
    for (int r = 0; r < 16; ++r) acc[r] = 0.0f;
    for (int k = 0; k < C1; ++k) {
        float w = Ws[k * C2 + c];
#pragma unroll
        for (int r = 0; r < 16; ++r)
            acc[r] = fmaf(Xs[(rg * 16 + r) * C1 + k], w, acc[r]);
    }
#pragma unroll
    for (int r = 0; r < 16; ++r) {
        int row = r0 + rg * 16 + r;
        if (row < N_NODES) h1[row * C2 + c] = acc[r];
    }
}

// ---------------- pull aggregation layer 1 (wave/node, register acc) ----------------
__global__ __launch_bounds__(256) void k_pull1(const int* __restrict__ rowstart,
                                               const int* __restrict__ indeg,
                                               const int* __restrict__ csr,
                                               const float* __restrict__ h1,
                                               const float* __restrict__ dinv,
                                               const float* __restrict__ b1,
                                               float* __restrict__ agg1) {
    int node = blockIdx.x * 4 + (threadIdx.x >> 6);
    if (node >= N_NODES) return;
    int lane = threadIdx.x & 63;
    int start = rowstart[node], end = start + indeg[node];
    float dd = dinv[node];
    float2 h = *(const float2*)(h1 + node * C2 + lane * 2);
    float2 b = *(const float2*)(b1 + lane * 2);
    float2 acc;
    acc.x = fmaf(h.x, dd * dd, b.x);
    acc.y = fmaf(h.y, dd * dd, b.y);
    for (int j0 = start; j0 < end; j0 += 64) {
        int n = end - j0; if (n > 64) n = 64;
        int idx = 0;
        if (lane < n) idx = csr[j0 + lane];
        float ds = dinv[idx];
        for (int k = 0; k < n; ++k) {
            int s = __shfl(idx, k);
            float w = __shfl(ds, k) * dd;
            float2 v = *(const float2*)(h1 + s * C2 + lane * 2);
            acc.x = fmaf(v.x, w, acc.x);
            acc.y = fmaf(v.y, w, acc.y);
        }
    }
    *(float2*)(agg1 + node * C2 + lane * 2) = acc;
}

// ---------------- BN stats ----------------
__global__ __launch_bounds__(256) void k_stats(const float* __restrict__ agg1,
                                               float* __restrict__ stats) {
    __shared__ float ls[256], lq[256];
    int tid = threadIdx.x;
    int c = tid & 127, half = tid >> 7;
    float s = 0.0f, q = 0.0f;
    for (int row = blockIdx.x * 2 + half; row < N_NODES; row += gridDim.x * 2) {
        float v = agg1[row * C2 + c];
        s += v; q += v * v;
    }
    ls[tid] = s; lq[tid] = q;
    __syncthreads();
    if (tid < 128) {
        s = ls[tid] + ls[tid + 128];
        q = lq[tid] + lq[tid + 128];
        unsafeAtomicAdd(&stats[c], s);
        unsafeAtomicAdd(&stats[128 + c], q);
    }
}

__global__ void k_bnparam(const float* __restrict__ gamma, const float* __restrict__ beta,
                          float* __restrict__ stats) {
    int c = threadIdx.x;
    if (c < 128) {
        const float invN = 1.0f / (float)N_NODES;
        float mean = stats[c] * invN;
        float var = stats[128 + c] * invN - mean * mean;
        float sc = gamma[c] * rsqrtf(var + 1e-5f);
        stats[256 + c] = sc;
        stats[384 + c] = beta[c] - mean * sc;
    }
}

// ---------------- GEMM2: h2 = relu(bn(agg1)) @ W2 ----------------
__global__ __launch_bounds__(256) void k_gemm2(const float* __restrict__ agg1,
                                               const float* __restrict__ W2,
                                               const float* __restrict__ stats,
                                               float* __restrict__ h2) {
    __shared__ float Ws[C2 * C3];   // 32 KB
    __shared__ float As[32 * C2];   // 16 KB
    int tid = threadIdx.x;
    int r0 = blockIdx.x * 32;
    for (int i = tid; i < C2 * C3; i += 256) Ws[i] = W2[i];
    for (int i = tid; i < 32 * C2; i += 256) {
        int row = r0 + (i >> 7);
        int cc = i & 127;
        float v = 0.0f;
        if (row < N_NODES)
            v = fmaxf(fmaf(agg1[row * C2 + cc], stats[256 + cc], stats[384 + cc]), 0.0f);
        As[i] = v;
    }
    __syncthreads();
    int c = tid & 63;
    int rg = tid >> 6;
    float acc[8];
#pragma unroll
    for (int r = 0; r < 8; ++r) acc[r] = 0.0f;
    for (int k = 0; k < C2; ++k) {
        float w = Ws[k * C3 + c];
#pragma unroll
        for (int r = 0; r < 8; ++r)
            acc[r] = fmaf(As[(rg * 8 + r) * C2 + k], w, acc[r]);
    }
#pragma unroll
    for (int r = 0; r < 8; ++r) {
        int row = r0 + rg * 8 + r;
        if (row < N_NODES) h2[row * C3 + c] = acc[r];
    }
}

// ---------------- pull aggregation layer 2 (wave/node, register acc) ----------------
__global__ __launch_bounds__(256) void k_pull2(const int* __restrict__ rowstart,
                                               const int* __restrict__ indeg,
                                               const int* __restrict__ csr,
                                               const float* __restrict__ h2,
                                               const float* __restrict__ dinv,
                                               const float* __restrict__ b2,
                                               float* __restrict__ out) {
    int node = blockIdx.x * 4 + (threadIdx.x >> 6);
    if (node >= N_NODES) return;
    int lane = threadIdx.x & 63;
    int start = rowstart[node], end = start + indeg[node];
    float dd = dinv[node];
    float h = h2[node * C3 + lane];
    float acc = fmaf(h, dd * dd, b2[lane]);
    for (int j0 = start; j0 < end; j0 += 64) {
        int n = end - j0; if (n > 64) n = 64;
        int idx = 0;
        if (lane < n) idx = csr[j0 + lane];
        float ds = dinv[idx];
        for (int k = 0; k < n; ++k) {
            int s = __shfl(idx, k);
            float w = __shfl(ds, k) * dd;
            acc = fmaf(h2[s * C3 + lane], w, acc);
        }
    }
    out[node * C3 + lane] = acc;
}

extern "C" void kernel_launch(void* const* d_in, const int* in_sizes, int n_in,
                              void* d_out, int out_size, void* d_ws, size_t ws_size,
                              hipStream_t stream) {
    const float* x     = (const float*)d_in[0];
    const int*   ei    = (const int*)d_in[1];
    const float* W1    = (const float*)d_in[2];
    const float* b1    = (const float*)d_in[3];
    const float* gamma = (const float*)d_in[4];
    const float* beta  = (const float*)d_in[5];
    const float* W2    = (const float*)d_in[6];
    const float* b2    = (const float*)d_in[7];
    float* out = (float*)d_out;

    int E = in_sizes[1] / 2;
    const int* src = ei;
    const int* dst = ei + E;

    // workspace layout (bytes), total 58,216,448 (<= known-good 58.4MB):
    //   0         dinv     [50176 f]   200704
    //   200704    stats    [512 f]     2048
    //   202752    indeg    [50176 i]   200704
    //   403456    bcount   [1024 i]    4096
    //   407552    bstart   [1024 i]    4096
    //   411648    bcursor  [1024 i]    4096
    //   415744    rowstart [50176 i]   200704
    //   616448    pairs/csr[1.6M i]    6400000
    //   7016448   h1/h2    [50000*128] 25600000
    //   32616448  agg1     [50000*128] 25600000
    char* ws = (char*)d_ws;
    float* dinv     = (float*)ws;
    float* stats    = (float*)(ws + 200704);
    int*   indeg    = (int*)(ws + 202752);
    int*   bcount   = (int*)(ws + 403456);
    int*   bstart   = (int*)(ws + 407552);
    int*   bcursor  = (int*)(ws + 411648);
    int*   rowstart = (int*)(ws + 415744);
    int*   pairs    = (int*)(ws + 616448);   // becomes node-major csr after k_refine
    float* h1       = (float*)(ws + 7016448);
    float* agg1     = (float*)(ws + 32616448);
    float* h2       = h1;   // h1 dead after k_pull1

    const int nblk_nodes = (N_NODES + 255) / 256;
    const int nblk_rows  = (N_NODES + 31) / 32;
    const int nblk_edge  = (E + 255) / 256;
    const int nblk_pull  = (N_NODES + 3) / 4;

    k_zero<<<nblk_nodes, 256, 0, stream>>>(indeg, bcount, stats);
    k_hist<<<256, 256, 0, stream>>>(dst, E, indeg, bcount);
    k_scanb<<<1, 1024, 0, stream>>>(bcount, bstart, bcursor);
    k_dinv<<<nblk_nodes, 256, 0, stream>>>(indeg, dinv);
    k_scatterc<<<nblk_edge, 256, 0, stream>>>(src, dst, E, bcursor, pairs);
    k_refine<<<NBUCK, 256, 0, stream>>>(bstart, bcount, indeg, rowstart, pairs);

    k_gemm1<<<nblk_rows, 256, 0, stream>>>(x, W1, h1);
    k_pull1<<<nblk_pull, 256, 0, stream>>>(rowstart, indeg, pairs, h1, dinv, b1, agg1);

    k_stats<<<256, 256, 0, stream>>>(agg1, stats);
    k_bnparam<<<1, 128, 0, stream>>>(gamma, beta, stats);

    k_gemm2<<<nblk_rows, 256, 0, stream>>>(agg1, W2, stats, h2);
    k_pull2<<<nblk_pull, 256, 0, stream>>>(rowstart, indeg, pairs, h2, dinv, b2, out);
}

// Round 7
// 501.773 us; speedup vs baseline: 5.3313x; 1.6861x over previous
//
#include <hip/hip_runtime.h>

#define N_NODES 50000
#define C1 64    // in channels
#define C2 128   // hidden
#define C3 64    // latent / out
#define NBUCK ((N_NODES + 63) / 64)   // 782 coarse buckets of 64 dst nodes
#define BCAP 8192                     // max edges per bucket (mean 2046, sigma 45)
#define STILE 4096                    // edges per scatter block (16 per thread)

// ---------------- zero indeg + bucket counts + stats ----------------
__global__ void k_zero(int* __restrict__ indeg, int* __restrict__ bcount,
                       float* __restrict__ stats) {
    int i = blockIdx.x * blockDim.x + threadIdx.x;
    if (i < N_NODES) indeg[i] = 0;
    if (i < NBUCK) bcount[i] = 0;
    if (i < 512) stats[i] = 0.0f;
}

// ---------------- fused: per-node indegree + coarse bucket histogram ----------------
__global__ __launch_bounds__(256) void k_hist(const int* __restrict__ dst, int E,
                                              int* __restrict__ indeg,
                                              int* __restrict__ bcount) {
    __shared__ int lh[NBUCK];
    int tid = threadIdx.x;
    for (int i = tid; i < NBUCK; i += 256) lh[i] = 0;
    __syncthreads();
    int stride = gridDim.x * blockDim.x;
    for (int e = blockIdx.x * blockDim.x + tid; e < E; e += stride) {
        int d = dst[e];
        atomicAdd(&indeg[d], 1);
        atomicAdd(&lh[d >> 6], 1);
    }
    __syncthreads();
    for (int i = tid; i < NBUCK; i += 256)
        if (lh[i]) atomicAdd(&bcount[i], lh[i]);
}

// ---------------- scan 782 bucket counts (single block); init PADDED cursors ----------------
__global__ __launch_bounds__(1024) void k_scanb(const int* __restrict__ bcount,
                                                int* __restrict__ bstart,
                                                int* __restrict__ bcursor) {
    __shared__ int sums[1024];
    int t = threadIdx.x;
    int v = (t < NBUCK) ? bcount[t] : 0;
    sums[t] = v;
    __syncthreads();
    for (int off = 1; off < 1024; off <<= 1) {
        int u = (t >= off) ? sums[t - off] : 0;
        __syncthreads();
        sums[t] += u;
        __syncthreads();
    }
    if (t < NBUCK) {
        int ex = sums[t] - v;
        bstart[t] = ex;
        bcursor[t * 16] = ex;   // one cursor per 64B line
    }
}

// ---------------- dinv ----------------
__global__ void k_dinv(const int* __restrict__ indeg, float* __restrict__ dinv) {
    int i = blockIdx.x * blockDim.x + threadIdx.x;
    if (i < N_NODES) dinv[i] = rsqrtf(1.0f + (float)indeg[i]);
}

// ---------------- coarse scatter v2: LDS-aggregated runs, padded cursors ----------------
__global__ __launch_bounds__(256) void k_scatterc(const int* __restrict__ src,
                                                  const int* __restrict__ dst, int E,
                                                  int* __restrict__ bcursor,
                                                  int* __restrict__ pairs) {
    __shared__ int lh[NBUCK];     // per-block bucket counts (then ranks)
    __shared__ int gbase[NBUCK];  // per-block reserved run base
    int tid = threadIdx.x;
    int base = blockIdx.x * STILE;
    for (int i = tid; i < NBUCK; i += 256) lh[i] = 0;
    __syncthreads();
    int sv[16], dv[16], rk[16];
#pragma unroll
    for (int k = 0; k < 16; ++k) {
        int e = base + k * 256 + tid;
        sv[k] = -1;
        if (e < E) {
            sv[k] = src[e];
            dv[k] = dst[e];
            rk[k] = atomicAdd(&lh[dv[k] >> 6], 1);
        }
    }
    __syncthreads();
    for (int i = tid; i < NBUCK; i += 256) {
        int c = lh[i];
        gbase[i] = c ? atomicAdd(&bcursor[i * 16], c) : 0;
    }
    __syncthreads();
#pragma unroll
    for (int k = 0; k < 16; ++k) {
        if (sv[k] >= 0) {
            int b = dv[k] >> 6;
            pairs[gbase[b] + rk[k]] = (sv[k] << 6) | (dv[k] & 63);
        }
    }
}

// ---------------- refine: in-place, bucket -> node-major CSR (+rowstart) ----------------
__global__ __launch_bounds__(256) void k_refine(const int* __restrict__ bstart,
                                                const int* __restrict__ bcount,
                                                const int* __restrict__ indeg,
                                                int* __restrict__ rowstart,
                                                int* __restrict__ pairs) {
    __shared__ int stage[BCAP];   // 32 KB
    __shared__ int lcur[64];
    int b = blockIdx.x;
    int tid = threadIdx.x;
    int e0 = bstart[b], n = bcount[b];
    if (tid < 64) {   // wave 0: shfl-scan the 64 node degrees
        int nd = b * 64 + tid;
        int dg = (nd < N_NODES) ? indeg[nd] : 0;
        int pfx = dg;
#pragma unroll
        for (int off = 1; off < 64; off <<= 1) {
            int v = __shfl_up(pfx, off);
            if (tid >= off) pfx += v;
        }
        int st = e0 + (pfx - dg);   // exclusive
        if (nd < N_NODES) rowstart[nd] = st;
        lcur[tid] = st;
    }
    for (int j = tid; j < n; j += 256) stage[j] = pairs[e0 + j];
    __syncthreads();
    for (int j = tid; j < n; j += 256) {
        int pk = stage[j];
        int pos = atomicAdd(&lcur[pk & 63], 1);
        pairs[pos] = pk >> 6;   // store src only, node-major
    }
}

// ---------------- GEMM1: h1 = x @ W1 ----------------
__global__ __launch_bounds__(256) void k_gemm1(const float* __restrict__ x,
                                               const float* __restrict__ W1,
                                               float* __restrict__ h1) {
    __shared__ float Ws[C1 * C2];   // 32 KB
    __shared__ float Xs[32 * C1];   //  8 KB
    int tid = threadIdx.x;
    int r0 = blockIdx.x * 32;
    for (int i = tid; i < C1 * C2; i += 256) Ws[i] = W1[i];
    for (int i = tid; i < 32 * C1; i += 256) {
        int row = r0 + (i >> 6);
        Xs[i] = (row < N_NODES) ? x[row * C1 + (i & 63)] : 0.0f;
    }
    __syncthreads();
    int c = tid & 127;
    int rg = tid >> 7;
    float acc[16];
#pragma unroll
    for (int r = 0; r < 16; ++r) acc[r] = 0.0f;
    for (int k = 0; k < C1; ++k) {
        float w = Ws[k * C2 + c];
#pragma unroll
        for (int r = 0; r < 16; ++r)
            acc[r] = fmaf(Xs[(rg * 16 + r) * C1 + k], w, acc[r]);
    }
#pragma unroll
    for (int r = 0; r < 16; ++r) {
        int row = r0 + rg * 16 + r;
        if (row < N_NODES) h1[row * C2 + c] = acc[r];
    }
}

// ---------------- pull aggregation layer 1 (wave/node, register acc) ----------------
__global__ __launch_bounds__(256) void k_pull1(const int* __restrict__ rowstart,
                                               const int* __restrict__ indeg,
                                               const int* __restrict__ csr,
                                               const float* __restrict__ h1,
                                               const float* __restrict__ dinv,
                                               const float* __restrict__ b1,
                                               float* __restrict__ agg1) {
    int node = blockIdx.x * 4 + (threadIdx.x >> 6);
    if (node >= N_NODES) return;
    int lane = threadIdx.x & 63;
    int start = rowstart[node], end = start + indeg[node];
    float dd = dinv[node];
    float2 h = *(const float2*)(h1 + node * C2 + lane * 2);
    float2 b = *(const float2*)(b1 + lane * 2);
    float2 acc;
    acc.x = fmaf(h.x, dd * dd, b.x);
    acc.y = fmaf(h.y, dd * dd, b.y);
    for (int j0 = start; j0 < end; j0 += 64) {
        int n = end - j0; if (n > 64) n = 64;
        int idx = 0;
        if (lane < n) idx = csr[j0 + lane];
        float ds = dinv[idx];
        for (int k = 0; k < n; ++k) {
            int s = __shfl(idx, k);
            float w = __shfl(ds, k) * dd;
            float2 v = *(const float2*)(h1 + s * C2 + lane * 2);
            acc.x = fmaf(v.x, w, acc.x);
            acc.y = fmaf(v.y, w, acc.y);
        }
    }
    *(float2*)(agg1 + node * C2 + lane * 2) = acc;
}

// ---------------- BN stats ----------------
__global__ __launch_bounds__(256) void k_stats(const float* __restrict__ agg1,
                                               float* __restrict__ stats) {
    __shared__ float ls[256], lq[256];
    int tid = threadIdx.x;
    int c = tid & 127, half = tid >> 7;
    float s = 0.0f, q = 0.0f;
    for (int row = blockIdx.x * 2 + half; row < N_NODES; row += gridDim.x * 2) {
        float v = agg1[row * C2 + c];
        s += v; q += v * v;
    }
    ls[tid] = s; lq[tid] = q;
    __syncthreads();
    if (tid < 128) {
        s = ls[tid] + ls[tid + 128];
        q = lq[tid] + lq[tid + 128];
        unsafeAtomicAdd(&stats[c], s);
        unsafeAtomicAdd(&stats[128 + c], q);
    }
}

__global__ void k_bnparam(const float* __restrict__ gamma, const float* __restrict__ beta,
                          float* __restrict__ stats) {
    int c = threadIdx.x;
    if (c < 128) {
        const float invN = 1.0f / (float)N_NODES;
        float mean = stats[c] * invN;
        float var = stats[128 + c] * invN - mean * mean;
        float sc = gamma[c] * rsqrtf(var + 1e-5f);
        stats[256 + c] = sc;
        stats[384 + c] = beta[c] - mean * sc;
    }
}

// ---------------- GEMM2: h2 = relu(bn(agg1)) @ W2 ----------------
__global__ __launch_bounds__(256) void k_gemm2(const float* __restrict__ agg1,
                                               const float* __restrict__ W2,
                                               const float* __restrict__ stats,
                                               float* __restrict__ h2) {
    __shared__ float Ws[C2 * C3];   // 32 KB
    __shared__ float As[32 * C2];   // 16 KB
    int tid = threadIdx.x;
    int r0 = blockIdx.x * 32;
    for (int i = tid; i < C2 * C3; i += 256) Ws[i] = W2[i];
    for (int i = tid; i < 32 * C2; i += 256) {
        int row = r0 + (i >> 7);
        int cc = i & 127;
        float v = 0.0f;
        if (row < N_NODES)
            v = fmaxf(fmaf(agg1[row * C2 + cc], stats[256 + cc], stats[384 + cc]), 0.0f);
        As[i] = v;
    }
    __syncthreads();
    int c = tid & 63;
    int rg = tid >> 6;
    float acc[8];
#pragma unroll
    for (int r = 0; r < 8; ++r) acc[r] = 0.0f;
    for (int k = 0; k < C2; ++k) {
        float w = Ws[k * C3 + c];
#pragma unroll
        for (int r = 0; r < 8; ++r)
            acc[r] = fmaf(As[(rg * 8 + r) * C2 + k], w, acc[r]);
    }
#pragma unroll
    for (int r = 0; r < 8; ++r) {
        int row = r0 + rg * 8 + r;
        if (row < N_NODES) h2[row * C3 + c] = acc[r];
    }
}

// ---------------- pull aggregation layer 2 (wave/node, register acc) ----------------
__global__ __launch_bounds__(256) void k_pull2(const int* __restrict__ rowstart,
                                               const int* __restrict__ indeg,
                                               const int* __restrict__ csr,
                                               const float* __restrict__ h2,
                                               const float* __restrict__ dinv,
                                               const float* __restrict__ b2,
                                               float* __restrict__ out) {
    int node = blockIdx.x * 4 + (threadIdx.x >> 6);
    if (node >= N_NODES) return;
    int lane = threadIdx.x & 63;
    int start = rowstart[node], end = start + indeg[node];
    float dd = dinv[node];
    float h = h2[node * C3 + lane];
    float acc = fmaf(h, dd * dd, b2[lane]);
    for (int j0 = start; j0 < end; j0 += 64) {
        int n = end - j0; if (n > 64) n = 64;
        int idx = 0;
        if (lane < n) idx = csr[j0 + lane];
        float ds = dinv[idx];
        for (int k = 0; k < n; ++k) {
            int s = __shfl(idx, k);
            float w = __shfl(ds, k) * dd;
            acc = fmaf(h2[s * C3 + lane], w, acc);
        }
    }
    out[node * C3 + lane] = acc;
}

extern "C" void kernel_launch(void* const* d_in, const int* in_sizes, int n_in,
                              void* d_out, int out_size, void* d_ws, size_t ws_size,
                              hipStream_t stream) {
    const float* x     = (const float*)d_in[0];
    const int*   ei    = (const int*)d_in[1];
    const float* W1    = (const float*)d_in[2];
    const float* b1    = (const float*)d_in[3];
    const float* gamma = (const float*)d_in[4];
    const float* beta  = (const float*)d_in[5];
    const float* W2    = (const float*)d_in[6];
    const float* b2    = (const float*)d_in[7];
    float* out = (float*)d_out;

    int E = in_sizes[1] / 2;
    const int* src = ei;
    const int* dst = ei + E;

    // workspace layout (bytes), total ~58.3MB:
    //   0         dinv      [50176 f]    200704
    //   200704    stats     [512 f]      2048
    //   202752    indeg     [50176 i]    200704
    //   403456    bcount    [1024 i]     4096
    //   407552    bstart    [1024 i]     4096
    //   411648    bcursor   [782*16 i]   50176 (padded: 1 cursor / 64B line)
    //   461824    rowstart  [50176 i]    200704
    //   662528    pairs/csr [1.6M i]     6400000
    //   7062528   h1/h2     [50000*128]  25600000
    //   32662528  agg1      [50000*128]  25600000  -> end 58262528
    char* ws = (char*)d_ws;
    float* dinv     = (float*)ws;
    float* stats    = (float*)(ws + 200704);
    int*   indeg    = (int*)(ws + 202752);
    int*   bcount   = (int*)(ws + 403456);
    int*   bstart   = (int*)(ws + 407552);
    int*   bcursor  = (int*)(ws + 411648);
    int*   rowstart = (int*)(ws + 461824);
    int*   pairs    = (int*)(ws + 662528);   // becomes node-major csr after k_refine
    float* h1       = (float*)(ws + 7062528);
    float* agg1     = (float*)(ws + 32662528);
    float* h2       = h1;   // h1 dead after k_pull1

    const int nblk_nodes = (N_NODES + 255) / 256;
    const int nblk_rows  = (N_NODES + 31) / 32;
    const int nblk_scat  = (E + STILE - 1) / STILE;   // 391
    const int nblk_pull  = (N_NODES + 3) / 4;

    k_zero<<<nblk_nodes, 256, 0, stream>>>(indeg, bcount, stats);
    k_hist<<<256, 256, 0, stream>>>(dst, E, indeg, bcount);
    k_scanb<<<1, 1024, 0, stream>>>(bcount, bstart, bcursor);
    k_dinv<<<nblk_nodes, 256, 0, stream>>>(indeg, dinv);
    k_scatterc<<<nblk_scat, 256, 0, stream>>>(src, dst, E, bcursor, pairs);
    k_refine<<<NBUCK, 256, 0, stream>>>(bstart, bcount, indeg, rowstart, pairs);

    k_gemm1<<<nblk_rows, 256, 0, stream>>>(x, W1, h1);
    k_pull1<<<nblk_pull, 256, 0, stream>>>(rowstart, indeg, pairs, h1, dinv, b1, agg1);

    k_stats<<<256, 256, 0, stream>>>(agg1, stats);
    k_bnparam<<<1, 128, 0, stream>>>(gamma, beta, stats);

    k_gemm2<<<nblk_rows, 256, 0, stream>>>(agg1, W2, stats, h2);
    k_pull2<<<nblk_pull, 256, 0, stream>>>(rowstart, indeg, pairs, h2, dinv, b2, out);
}

// Round 8
// 334.488 us; speedup vs baseline: 7.9976x; 1.5001x over previous
//
#include <hip/hip_runtime.h>

#define N_NODES 50000
#define C1 64    // in channels
#define C2 128   // hidden
#define C3 64    // latent / out
#define NBUCK ((N_NODES + 63) / 64)   // 782 coarse buckets of 64 dst nodes
#define BCAP 8192                     // max edges per bucket (mean 2046, sigma 45)
#define STILE 4096                    // edges per scatter block (16 per thread)

// ---------------- zero bucket counts + stats ----------------
__global__ void k_zero(int* __restrict__ bcount, float* __restrict__ stats) {
    int i = blockIdx.x * blockDim.x + threadIdx.x;
    if (i < NBUCK) bcount[i] = 0;
    if (i < 512) stats[i] = 0.0f;
}

// ---------------- coarse bucket histogram (LDS-privatized) ----------------
__global__ __launch_bounds__(256) void k_hist(const int* __restrict__ dst, int E,
                                              int* __restrict__ bcount) {
    __shared__ int lh[NBUCK];
    int tid = threadIdx.x;
    for (int i = tid; i < NBUCK; i += 256) lh[i] = 0;
    __syncthreads();
    int stride = gridDim.x * blockDim.x;
    for (int e = blockIdx.x * blockDim.x + tid; e < E; e += stride)
        atomicAdd(&lh[dst[e] >> 6], 1);
    __syncthreads();
    for (int i = tid; i < NBUCK; i += 256)
        if (lh[i]) atomicAdd(&bcount[i], lh[i]);
}

// ---------------- scan 782 bucket counts (single block); init PADDED cursors ----------------
__global__ __launch_bounds__(1024) void k_scanb(const int* __restrict__ bcount,
                                                int* __restrict__ bstart,
                                                int* __restrict__ bcursor) {
    __shared__ int sums[1024];
    int t = threadIdx.x;
    int v = (t < NBUCK) ? bcount[t] : 0;
    sums[t] = v;
    __syncthreads();
    for (int off = 1; off < 1024; off <<= 1) {
        int u = (t >= off) ? sums[t - off] : 0;
        __syncthreads();
        sums[t] += u;
        __syncthreads();
    }
    if (t < NBUCK) {
        int ex = sums[t] - v;
        bstart[t] = ex;
        bcursor[t * 16] = ex;   // one cursor per 64B line
    }
}

// ---------------- coarse scatter: LDS-aggregated runs, padded cursors ----------------
__global__ __launch_bounds__(256) void k_scatterc(const int* __restrict__ src,
                                                  const int* __restrict__ dst, int E,
                                                  int* __restrict__ bcursor,
                                                  int* __restrict__ pairs) {
    __shared__ int lh[NBUCK];     // per-block bucket counts (ranks)
    __shared__ int gbase[NBUCK];  // per-block reserved run base
    int tid = threadIdx.x;
    int base = blockIdx.x * STILE;
    for (int i = tid; i < NBUCK; i += 256) lh[i] = 0;
    __syncthreads();
    int sv[16], dv[16], rk[16];
#pragma unroll
    for (int k = 0; k < 16; ++k) {
        int e = base + k * 256 + tid;
        sv[k] = -1;
        if (e < E) {
            sv[k] = src[e];
            dv[k] = dst[e];
            rk[k] = atomicAdd(&lh[dv[k] >> 6], 1);
        }
    }
    __syncthreads();
    for (int i = tid; i < NBUCK; i += 256) {
        int c = lh[i];
        gbase[i] = c ? atomicAdd(&bcursor[i * 16], c) : 0;
    }
    __syncthreads();
#pragma unroll
    for (int k = 0; k < 16; ++k) {
        if (sv[k] >= 0) {
            int b = dv[k] >> 6;
            pairs[gbase[b] + rk[k]] = (sv[k] << 6) | (dv[k] & 63);
        }
    }
}

// ---------------- refine: bucket -> node-major CSR; computes rowstart + dinv in-kernel ----------------
__global__ __launch_bounds__(256) void k_refine(const int* __restrict__ bstart,
                                                const int* __restrict__ bcount,
                                                int* __restrict__ rowstart,
                                                float* __restrict__ dinv,
                                                int* __restrict__ pairs) {
    __shared__ int stage[BCAP];   // 32 KB
    __shared__ int lcnt[64];
    __shared__ int lcur[64];
    int b = blockIdx.x;
    int tid = threadIdx.x;
    int e0 = bstart[b], n = bcount[b];
    if (tid < 64) lcnt[tid] = 0;
    __syncthreads();
    for (int j = tid; j < n; j += 256) {
        int pk = pairs[e0 + j];
        stage[j] = pk;
        atomicAdd(&lcnt[pk & 63], 1);
    }
    __syncthreads();
    if (tid < 64) {   // wave 0: shfl-scan the 64 local degrees
        int dg = lcnt[tid];
        int pfx = dg;
#pragma unroll
        for (int off = 1; off < 64; off <<= 1) {
            int v = __shfl_up(pfx, off);
            if (tid >= off) pfx += v;
        }
        int st = e0 + (pfx - dg);   // exclusive
        int nd = b * 64 + tid;
        rowstart[nd] = st;          // padding slots get valid boundaries too
        dinv[nd] = rsqrtf(1.0f + (float)dg);
        lcur[tid] = st;
    }
    __syncthreads();
    for (int j = tid; j < n; j += 256) {
        int pk = stage[j];
        int pos = atomicAdd(&lcur[pk & 63], 1);
        pairs[pos] = pk >> 6;   // store src only, node-major
    }
}

// ---------------- pull x (64 ch): aggx = sum norm*x[src] + dinv^2*x[node] ----------------
__global__ __launch_bounds__(256) void k_pullx(const int* __restrict__ rowstart,
                                               const int* __restrict__ csr,
                                               const float* __restrict__ x,
                                               const float* __restrict__ dinv,
                                               float* __restrict__ aggx) {
    int node = blockIdx.x * 4 + (threadIdx.x >> 6);
    if (node >= N_NODES) return;
    int lane = threadIdx.x & 63;
    int start = rowstart[node], end = rowstart[node + 1];
    float dd = dinv[node];
    float acc = x[node * C1 + lane] * dd * dd;
    for (int j0 = start; j0 < end; j0 += 64) {
        int n = end - j0; if (n > 64) n = 64;
        int idx = 0;
        if (lane < n) idx = csr[j0 + lane];
        float ds = dinv[idx];
        int k = 0;
        for (; k + 3 < n; k += 4) {
            int s0 = __shfl(idx, k),     s1 = __shfl(idx, k + 1);
            int s2 = __shfl(idx, k + 2), s3 = __shfl(idx, k + 3);
            float w0 = __shfl(ds, k) * dd,     w1 = __shfl(ds, k + 1) * dd;
            float w2 = __shfl(ds, k + 2) * dd, w3 = __shfl(ds, k + 3) * dd;
            float v0 = x[s0 * C1 + lane], v1 = x[s1 * C1 + lane];
            float v2 = x[s2 * C1 + lane], v3 = x[s3 * C1 + lane];
            acc = fmaf(v0, w0, acc); acc = fmaf(v1, w1, acc);
            acc = fmaf(v2, w2, acc); acc = fmaf(v3, w3, acc);
        }
        for (; k < n; ++k) {
            int s = __shfl(idx, k);
            float w = __shfl(ds, k) * dd;
            acc = fmaf(x[s * C1 + lane], w, acc);
        }
    }
    aggx[node * C1 + lane] = acc;
}

// ---------------- GEMM1: agg1 = aggx @ W1 + b1 ----------------
__global__ __launch_bounds__(256) void k_gemm1b(const float* __restrict__ aggx,
                                                const float* __restrict__ W1,
                                                const float* __restrict__ b1,
                                                float* __restrict__ agg1) {
    __shared__ float Ws[C1 * C2];   // 32 KB
    __shared__ float Xs[32 * C1];   //  8 KB
    int tid = threadIdx.x;
    int r0 = blockIdx.x * 32;
    for (int i = tid; i < C1 * C2; i += 256) Ws[i] = W1[i];
    for (int i = tid; i < 32 * C1; i += 256) {
        int row = r0 + (i >> 6);
        Xs[i] = (row < N_NODES) ? aggx[row * C1 + (i & 63)] : 0.0f;
    }
    __syncthreads();
    int c = tid & 127;
    int rg = tid >> 7;
    float bv = b1[c];
    float acc[16];
#pragma unroll
    for (int r = 0; r < 16; ++r) acc[r] = 0.0f;
    for (int k = 0; k < C1; ++k) {
        float w = Ws[k * C2 + c];
#pragma unroll
        for (int r = 0; r < 16; ++r)
            acc[r] = fmaf(Xs[(rg * 16 + r) * C1 + k], w, acc[r]);
    }
#pragma unroll
    for (int r = 0; r < 16; ++r) {
        int row = r0 + rg * 16 + r;
        if (row < N_NODES) agg1[row * C2 + c] = acc[r] + bv;
    }
}

// ---------------- BN stats ----------------
__global__ __launch_bounds__(256) void k_stats(const float* __restrict__ agg1,
                                               float* __restrict__ stats) {
    __shared__ float ls[256], lq[256];
    int tid = threadIdx.x;
    int c = tid & 127, half = tid >> 7;
    float s = 0.0f, q = 0.0f;
    for (int row = blockIdx.x * 2 + half; row < N_NODES; row += gridDim.x * 2) {
        float v = agg1[row * C2 + c];
        s += v; q += v * v;
    }
    ls[tid] = s; lq[tid] = q;
    __syncthreads();
    if (tid < 128) {
        s = ls[tid] + ls[tid + 128];
        q = lq[tid] + lq[tid + 128];
        unsafeAtomicAdd(&stats[c], s);
        unsafeAtomicAdd(&stats[128 + c], q);
    }
}

__global__ void k_bnparam(const float* __restrict__ gamma, const float* __restrict__ beta,
                          float* __restrict__ stats) {
    int c = threadIdx.x;
    if (c < 128) {
        const float invN = 1.0f / (float)N_NODES;
        float mean = stats[c] * invN;
        float var = stats[128 + c] * invN - mean * mean;
        float sc = gamma[c] * rsqrtf(var + 1e-5f);
        stats[256 + c] = sc;
        stats[384 + c] = beta[c] - mean * sc;
    }
}

// ---------------- GEMM2: h2 = relu(bn(agg1)) @ W2 ----------------
__global__ __launch_bounds__(256) void k_gemm2(const float* __restrict__ agg1,
                                               const float* __restrict__ W2,
                                               const float* __restrict__ stats,
                                               float* __restrict__ h2) {
    __shared__ float Ws[C2 * C3];   // 32 KB
    __shared__ float As[32 * C2];   // 16 KB
    int tid = threadIdx.x;
    int r0 = blockIdx.x * 32;
    for (int i = tid; i < C2 * C3; i += 256) Ws[i] = W2[i];
    for (int i = tid; i < 32 * C2; i += 256) {
        int row = r0 + (i >> 7);
        int cc = i & 127;
        float v = 0.0f;
        if (row < N_NODES)
            v = fmaxf(fmaf(agg1[row * C2 + cc], stats[256 + cc], stats[384 + cc]), 0.0f);
        As[i] = v;
    }
    __syncthreads();
    int c = tid & 63;
    int rg = tid >> 6;
    float acc[8];
#pragma unroll
    for (int r = 0; r < 8; ++r) acc[r] = 0.0f;
    for (int k = 0; k < C2; ++k) {
        float w = Ws[k * C3 + c];
#pragma unroll
        for (int r = 0; r < 8; ++r)
            acc[r] = fmaf(As[(rg * 8 + r) * C2 + k], w, acc[r]);
    }
#pragma unroll
    for (int r = 0; r < 8; ++r) {
        int row = r0 + rg * 8 + r;
        if (row < N_NODES) h2[row * C3 + c] = acc[r];
    }
}

// ---------------- pull layer 2 (64 ch), 4-way unrolled ----------------
__global__ __launch_bounds__(256) void k_pull2(const int* __restrict__ rowstart,
                                               const int* __restrict__ csr,
                                               const float* __restrict__ h2,
                                               const float* __restrict__ dinv,
                                               const float* __restrict__ b2,
                                               float* __restrict__ out) {
    int node = blockIdx.x * 4 + (threadIdx.x >> 6);
    if (node >= N_NODES) return;
    int lane = threadIdx.x & 63;
    int start = rowstart[node], end = rowstart[node + 1];
    float dd = dinv[node];
    float acc = fmaf(h2[node * C3 + lane], dd * dd, b2[lane]);
    for (int j0 = start; j0 < end; j0 += 64) {
        int n = end - j0; if (n > 64) n = 64;
        int idx = 0;
        if (lane < n) idx = csr[j0 + lane];
        float ds = dinv[idx];
        int k = 0;
        for (; k + 3 < n; k += 4) {
            int s0 = __shfl(idx, k),     s1 = __shfl(idx, k + 1);
            int s2 = __shfl(idx, k + 2), s3 = __shfl(idx, k + 3);
            float w0 = __shfl(ds, k) * dd,     w1 = __shfl(ds, k + 1) * dd;
            float w2 = __shfl(ds, k + 2) * dd, w3 = __shfl(ds, k + 3) * dd;
            float v0 = h2[s0 * C3 + lane], v1 = h2[s1 * C3 + lane];
            float v2 = h2[s2 * C3 + lane], v3 = h2[s3 * C3 + lane];
            acc = fmaf(v0, w0, acc); acc = fmaf(v1, w1, acc);
            acc = fmaf(v2, w2, acc); acc = fmaf(v3, w3, acc);
        }
        for (; k < n; ++k) {
            int s = __shfl(idx, k);
            float w = __shfl(ds, k) * dd;
            acc = fmaf(h2[s * C3 + lane], w, acc);
        }
    }
    out[node * C3 + lane] = acc;
}

extern "C" void kernel_launch(void* const* d_in, const int* in_sizes, int n_in,
                              void* d_out, int out_size, void* d_ws, size_t ws_size,
                              hipStream_t stream) {
    const float* x     = (const float*)d_in[0];
    const int*   ei    = (const int*)d_in[1];
    const float* W1    = (const float*)d_in[2];
    const float* b1    = (const float*)d_in[3];
    const float* gamma = (const float*)d_in[4];
    const float* beta  = (const float*)d_in[5];
    const float* W2    = (const float*)d_in[6];
    const float* b2    = (const float*)d_in[7];
    float* out = (float*)d_out;

    int E = in_sizes[1] / 2;
    const int* src = ei;
    const int* dst = ei + E;

    // workspace layout (bytes), total ~58.1MB:
    //   0         dinv      [50176 f]    200704
    //   200704    stats     [512 f]      2048
    //   202752    bcount    [1024 i]     4096
    //   206848    bstart    [1024 i]     4096
    //   210944    bcursor   [782*16 i]   50176 (1 cursor / 64B line)
    //   261120    rowstart  [50176 i]    200704
    //   461824    pairs/csr [1.6M i]     6400000
    //   6861824   aggx      [50000*64]   12800000
    //   19661824  agg1      [50000*128]  25600000
    //   45261824  h2        [50000*64]   12800000  -> end 58061824
    char* ws = (char*)d_ws;
    float* dinv     = (float*)ws;
    float* stats    = (float*)(ws + 200704);
    int*   bcount   = (int*)(ws + 202752);
    int*   bstart   = (int*)(ws + 206848);
    int*   bcursor  = (int*)(ws + 210944);
    int*   rowstart = (int*)(ws + 261120);
    int*   pairs    = (int*)(ws + 461824);   // becomes node-major csr after k_refine
    float* aggx     = (float*)(ws + 6861824);
    float* agg1     = (float*)(ws + 19661824);
    float* h2       = (float*)(ws + 45261824);

    const int nblk_nodes = (N_NODES + 255) / 256;
    const int nblk_rows  = (N_NODES + 31) / 32;
    const int nblk_scat  = (E + STILE - 1) / STILE;   // 391
    const int nblk_pull  = (N_NODES + 3) / 4;

    k_zero<<<nblk_nodes, 256, 0, stream>>>(bcount, stats);
    k_hist<<<256, 256, 0, stream>>>(dst, E, bcount);
    k_scanb<<<1, 1024, 0, stream>>>(bcount, bstart, bcursor);
    k_scatterc<<<nblk_scat, 256, 0, stream>>>(src, dst, E, bcursor, pairs);
    k_refine<<<NBUCK, 256, 0, stream>>>(bstart, bcount, rowstart, dinv, pairs);

    k_pullx<<<nblk_pull, 256, 0, stream>>>(rowstart, pairs, x, dinv, aggx);
    k_gemm1b<<<nblk_rows, 256, 0, stream>>>(aggx, W1, b1, agg1);

    k_stats<<<256, 256, 0, stream>>>(agg1, stats);
    k_bnparam<<<1, 128, 0, stream>>>(gamma, beta, stats);

    k_gemm2<<<nblk_rows, 256, 0, stream>>>(agg1, W2, stats, h2);
    k_pull2<<<nblk_pull, 256, 0, stream>>>(rowstart, pairs, h2, dinv, b2, out);
}

// Round 9
// 319.931 us; speedup vs baseline: 8.3615x; 1.0455x over previous
//
#include <hip/hip_runtime.h>

#define N_NODES 50000
#define C1 64    // in channels
#define C2 128   // hidden
#define C3 64    // latent / out
#define NBUCK ((N_NODES + 63) / 64)   // 782 coarse buckets of 64 dst nodes
#define BCAP 8192                     // max edges per bucket (mean 2046, sigma 45)
#define STILE 4096                    // edges per scatter block (16 per thread)

__device__ __forceinline__ float bf2f(unsigned short u) {
    union { unsigned int i; float f; } v; v.i = ((unsigned int)u) << 16; return v.f;
}
__device__ __forceinline__ unsigned short f2bf(float f) {
    union { float f; unsigned int i; } v; v.f = f;
    return (unsigned short)((v.i + 0x7FFFu + ((v.i >> 16) & 1u)) >> 16);
}

// ---------------- zero bucket counts + stats, cast x -> bf16 ----------------
__global__ void k_zero_cast(const float* __restrict__ x, unsigned short* __restrict__ xh,
                            int* __restrict__ bcount, float* __restrict__ stats) {
    int i = blockIdx.x * blockDim.x + threadIdx.x;
    if (i < NBUCK) bcount[i] = 0;
    if (i < 512) stats[i] = 0.0f;
    if (i < N_NODES * C1 / 4) {
        float4 v = ((const float4*)x)[i];
        ushort4 o;
        o.x = f2bf(v.x); o.y = f2bf(v.y); o.z = f2bf(v.z); o.w = f2bf(v.w);
        ((ushort4*)xh)[i] = o;
    }
}

// ---------------- coarse bucket histogram (LDS-privatized) ----------------
__global__ __launch_bounds__(256) void k_hist(const int* __restrict__ dst, int E,
                                              int* __restrict__ bcount) {
    __shared__ int lh[NBUCK];
    int tid = threadIdx.x;
    for (int i = tid; i < NBUCK; i += 256) lh[i] = 0;
    __syncthreads();
    int stride = gridDim.x * blockDim.x;
    for (int e = blockIdx.x * blockDim.x + tid; e < E; e += stride)
        atomicAdd(&lh[dst[e] >> 6], 1);
    __syncthreads();
    for (int i = tid; i < NBUCK; i += 256)
        if (lh[i]) atomicAdd(&bcount[i], lh[i]);
}

// ---------------- scan 782 bucket counts (single block); init PADDED cursors ----------------
__global__ __launch_bounds__(1024) void k_scanb(const int* __restrict__ bcount,
                                                int* __restrict__ bstart,
                                                int* __restrict__ bcursor) {
    __shared__ int sums[1024];
    int t = threadIdx.x;
    int v = (t < NBUCK) ? bcount[t] : 0;
    sums[t] = v;
    __syncthreads();
    for (int off = 1; off < 1024; off <<= 1) {
        int u = (t >= off) ? sums[t - off] : 0;
        __syncthreads();
        sums[t] += u;
        __syncthreads();
    }
    if (t < NBUCK) {
        int ex = sums[t] - v;
        bstart[t] = ex;
        bcursor[t * 16] = ex;   // one cursor per 64B line
    }
}

// ---------------- coarse scatter: LDS-aggregated runs, padded cursors ----------------
__global__ __launch_bounds__(256) void k_scatterc(const int* __restrict__ src,
                                                  const int* __restrict__ dst, int E,
                                                  int* __restrict__ bcursor,
                                                  int* __restrict__ pairs) {
    __shared__ int lh[NBUCK];     // per-block bucket counts (ranks)
    __shared__ int gbase[NBUCK];  // per-block reserved run base
    int tid = threadIdx.x;
    int base = blockIdx.x * STILE;
    for (int i = tid; i < NBUCK; i += 256) lh[i] = 0;
    __syncthreads();
    int sv[16], dv[16], rk[16];
#pragma unroll
    for (int k = 0; k < 16; ++k) {
        int e = base + k * 256 + tid;
        sv[k] = -1;
        if (e < E) {
            sv[k] = src[e];
            dv[k] = dst[e];
            rk[k] = atomicAdd(&lh[dv[k] >> 6], 1);
        }
    }
    __syncthreads();
    for (int i = tid; i < NBUCK; i += 256) {
        int c = lh[i];
        gbase[i] = c ? atomicAdd(&bcursor[i * 16], c) : 0;
    }
    __syncthreads();
#pragma unroll
    for (int k = 0; k < 16; ++k) {
        if (sv[k] >= 0) {
            int b = dv[k] >> 6;
            pairs[gbase[b] + rk[k]] = (sv[k] << 6) | (dv[k] & 63);
        }
    }
}

// ---------------- refine: bucket -> node-major CSR; computes rowstart + dinv in-kernel ----------------
__global__ __launch_bounds__(256) void k_refine(const int* __restrict__ bstart,
                                                const int* __restrict__ bcount,
                                                int* __restrict__ rowstart,
                                                float* __restrict__ dinv,
                                                int* __restrict__ pairs) {
    __shared__ int stage[BCAP];   // 32 KB
    __shared__ int lcnt[64];
    __shared__ int lcur[64];
    int b = blockIdx.x;
    int tid = threadIdx.x;
    int e0 = bstart[b], n = bcount[b];
    if (tid < 64) lcnt[tid] = 0;
    __syncthreads();
    for (int j = tid; j < n; j += 256) {
        int pk = pairs[e0 + j];
        stage[j] = pk;
        atomicAdd(&lcnt[pk & 63], 1);
    }
    __syncthreads();
    if (tid < 64) {   // wave 0: shfl-scan the 64 local degrees
        int dg = lcnt[tid];
        int pfx = dg;
#pragma unroll
        for (int off = 1; off < 64; off <<= 1) {
            int v = __shfl_up(pfx, off);
            if (tid >= off) pfx += v;
        }
        int st = e0 + (pfx - dg);   // exclusive
        int nd = b * 64 + tid;
        rowstart[nd] = st;          // padding slots get valid boundaries too
        dinv[nd] = rsqrtf(1.0f + (float)dg);
        lcur[tid] = st;
    }
    __syncthreads();
    for (int j = tid; j < n; j += 256) {
        int pk = stage[j];
        int pos = atomicAdd(&lcur[pk & 63], 1);
        pairs[pos] = pk >> 6;   // store src only, node-major
    }
}

// ---------------- pull x (64 ch, bf16 gather): aggx = sum norm*x[src] + dinv^2*x[node] ----------------
__global__ __launch_bounds__(256) void k_pullx(const int* __restrict__ rowstart,
                                               const int* __restrict__ csr,
                                               const float* __restrict__ x,
                                               const unsigned short* __restrict__ xh,
                                               const float* __restrict__ dinv,
                                               float* __restrict__ aggx) {
    int node = blockIdx.x * 4 + (threadIdx.x >> 6);
    if (node >= N_NODES) return;
    int lane = threadIdx.x & 63;
    int start = rowstart[node], end = rowstart[node + 1];
    float dd = dinv[node];
    float acc = x[node * C1 + lane] * dd * dd;   // exact fp32 self-term
    for (int j0 = start; j0 < end; j0 += 64) {
        int n = end - j0; if (n > 64) n = 64;
        int idx = 0;
        if (lane < n) idx = csr[j0 + lane];
        float ds = dinv[idx];
        int k = 0;
        for (; k + 3 < n; k += 4) {
            int s0 = __shfl(idx, k),     s1 = __shfl(idx, k + 1);
            int s2 = __shfl(idx, k + 2), s3 = __shfl(idx, k + 3);
            float w0 = __shfl(ds, k) * dd,     w1 = __shfl(ds, k + 1) * dd;
            float w2 = __shfl(ds, k + 2) * dd, w3 = __shfl(ds, k + 3) * dd;
            float v0 = bf2f(xh[s0 * C1 + lane]), v1 = bf2f(xh[s1 * C1 + lane]);
            float v2 = bf2f(xh[s2 * C1 + lane]), v3 = bf2f(xh[s3 * C1 + lane]);
            acc = fmaf(v0, w0, acc); acc = fmaf(v1, w1, acc);
            acc = fmaf(v2, w2, acc); acc = fmaf(v3, w3, acc);
        }
        for (; k < n; ++k) {
            int s = __shfl(idx, k);
            float w = __shfl(ds, k) * dd;
            acc = fmaf(bf2f(xh[s * C1 + lane]), w, acc);
        }
    }
    aggx[node * C1 + lane] = acc;
}

// ---------------- GEMM1: agg1 = aggx @ W1 + b1 ----------------
__global__ __launch_bounds__(256) void k_gemm1b(const float* __restrict__ aggx,
                                                const float* __restrict__ W1,
                                                const float* __restrict__ b1,
                                                float* __restrict__ agg1) {
    __shared__ float Ws[C1 * C2];   // 32 KB
    __shared__ float Xs[32 * C1];   //  8 KB
    int tid = threadIdx.x;
    int r0 = blockIdx.x * 32;
    for (int i = tid; i < C1 * C2; i += 256) Ws[i] = W1[i];
    for (int i = tid; i < 32 * C1; i += 256) {
        int row = r0 + (i >> 6);
        Xs[i] = (row < N_NODES) ? aggx[row * C1 + (i & 63)] : 0.0f;
    }
    __syncthreads();
    int c = tid & 127;
    int rg = tid >> 7;
    float bv = b1[c];
    float acc[16];
#pragma unroll
    for (int r = 0; r < 16; ++r) acc[r] = 0.0f;
    for (int k = 0; k < C1; ++k) {
        float w = Ws[k * C2 + c];
#pragma unroll
        for (int r = 0; r < 16; ++r)
            acc[r] = fmaf(Xs[(rg * 16 + r) * C1 + k], w, acc[r]);
    }
#pragma unroll
    for (int r = 0; r < 16; ++r) {
        int row = r0 + rg * 16 + r;
        if (row < N_NODES) agg1[row * C2 + c] = acc[r] + bv;
    }
}

// ---------------- BN stats ----------------
__global__ __launch_bounds__(256) void k_stats(const float* __restrict__ agg1,
                                               float* __restrict__ stats) {
    __shared__ float ls[256], lq[256];
    int tid = threadIdx.x;
    int c = tid & 127, half = tid >> 7;
    float s = 0.0f, q = 0.0f;
    for (int row = blockIdx.x * 2 + half; row < N_NODES; row += gridDim.x * 2) {
        float v = agg1[row * C2 + c];
        s += v; q += v * v;
    }
    ls[tid] = s; lq[tid] = q;
    __syncthreads();
    if (tid < 128) {
        s = ls[tid] + ls[tid + 128];
        q = lq[tid] + lq[tid + 128];
        unsafeAtomicAdd(&stats[c], s);
        unsafeAtomicAdd(&stats[128 + c], q);
    }
}

__global__ void k_bnparam(const float* __restrict__ gamma, const float* __restrict__ beta,
                          float* __restrict__ stats) {
    int c = threadIdx.x;
    if (c < 128) {
        const float invN = 1.0f / (float)N_NODES;
        float mean = stats[c] * invN;
        float var = stats[128 + c] * invN - mean * mean;
        float sc = gamma[c] * rsqrtf(var + 1e-5f);
        stats[256 + c] = sc;
        stats[384 + c] = beta[c] - mean * sc;
    }
}

// ---------------- GEMM2: h2 = relu(bn(agg1)) @ W2, bf16 output ----------------
__global__ __launch_bounds__(256) void k_gemm2(const float* __restrict__ agg1,
                                               const float* __restrict__ W2,
                                               const float* __restrict__ stats,
                                               unsigned short* __restrict__ h2h) {
    __shared__ float Ws[C2 * C3];   // 32 KB
    __shared__ float As[32 * C2];   // 16 KB
    int tid = threadIdx.x;
    int r0 = blockIdx.x * 32;
    for (int i = tid; i < C2 * C3; i += 256) Ws[i] = W2[i];
    for (int i = tid; i < 32 * C2; i += 256) {
        int row = r0 + (i >> 7);
        int cc = i & 127;
        float v = 0.0f;
        if (row < N_NODES)
            v = fmaxf(fmaf(agg1[row * C2 + cc], stats[256 + cc], stats[384 + cc]), 0.0f);
        As[i] = v;
    }
    __syncthreads();
    int c = tid & 63;
    int rg = tid >> 6;
    float acc[8];
#pragma unroll
    for (int r = 0; r < 8; ++r) acc[r] = 0.0f;
    for (int k = 0; k < C2; ++k) {
        float w = Ws[k * C3 + c];
#pragma unroll
        for (int r = 0; r < 8; ++r)
            acc[r] = fmaf(As[(rg * 8 + r) * C2 + k], w, acc[r]);
    }
#pragma unroll
    for (int r = 0; r < 8; ++r) {
        int row = r0 + rg * 8 + r;
        if (row < N_NODES) h2h[row * C3 + c] = f2bf(acc[r]);
    }
}

// ---------------- pull layer 2 (64 ch, bf16 gather), 4-way unrolled ----------------
__global__ __launch_bounds__(256) void k_pull2(const int* __restrict__ rowstart,
                                               const int* __restrict__ csr,
                                               const unsigned short* __restrict__ h2h,
                                               const float* __restrict__ dinv,
                                               const float* __restrict__ b2,
                                               float* __restrict__ out) {
    int node = blockIdx.x * 4 + (threadIdx.x >> 6);
    if (node >= N_NODES) return;
    int lane = threadIdx.x & 63;
    int start = rowstart[node], end = rowstart[node + 1];
    float dd = dinv[node];
    float acc = fmaf(bf2f(h2h[node * C3 + lane]), dd * dd, b2[lane]);
    for (int j0 = start; j0 < end; j0 += 64) {
        int n = end - j0; if (n > 64) n = 64;
        int idx = 0;
        if (lane < n) idx = csr[j0 + lane];
        float ds = dinv[idx];
        int k = 0;
        for (; k + 3 < n; k += 4) {
            int s0 = __shfl(idx, k),     s1 = __shfl(idx, k + 1);
            int s2 = __shfl(idx, k + 2), s3 = __shfl(idx, k + 3);
            float w0 = __shfl(ds, k) * dd,     w1 = __shfl(ds, k + 1) * dd;
            float w2 = __shfl(ds, k + 2) * dd, w3 = __shfl(ds, k + 3) * dd;
            float v0 = bf2f(h2h[s0 * C3 + lane]), v1 = bf2f(h2h[s1 * C3 + lane]);
            float v2 = bf2f(h2h[s2 * C3 + lane]), v3 = bf2f(h2h[s3 * C3 + lane]);
            acc = fmaf(v0, w0, acc); acc = fmaf(v1, w1, acc);
            acc = fmaf(v2, w2, acc); acc = fmaf(v3, w3, acc);
        }
        for (; k < n; ++k) {
            int s = __shfl(idx, k);
            float w = __shfl(ds, k) * dd;
            acc = fmaf(bf2f(h2h[s * C3 + lane]), w, acc);
        }
    }
    out[node * C3 + lane] = acc;
}

extern "C" void kernel_launch(void* const* d_in, const int* in_sizes, int n_in,
                              void* d_out, int out_size, void* d_ws, size_t ws_size,
                              hipStream_t stream) {
    const float* x     = (const float*)d_in[0];
    const int*   ei    = (const int*)d_in[1];
    const float* W1    = (const float*)d_in[2];
    const float* b1    = (const float*)d_in[3];
    const float* gamma = (const float*)d_in[4];
    const float* beta  = (const float*)d_in[5];
    const float* W2    = (const float*)d_in[6];
    const float* b2    = (const float*)d_in[7];
    float* out = (float*)d_out;

    int E = in_sizes[1] / 2;
    const int* src = ei;
    const int* dst = ei + E;

    // workspace layout (bytes), total ~58.1MB:
    //   0         dinv      [50176 f]    200704
    //   200704    stats     [512 f]      2048
    //   202752    bcount    [1024 i]     4096
    //   206848    bstart    [1024 i]     4096
    //   210944    bcursor   [782*16 i]   50176 (1 cursor / 64B line)
    //   261120    rowstart  [50176 i]    200704
    //   461824    pairs/csr [1.6M i]     6400000
    //   6861824   xh (bf16) [50000*64]   6400000
    //   13261824  aggx      [50000*64]   12800000
    //   26061824  agg1      [50000*128]  25600000
    //   51661824  h2h (bf16)[50000*64]   6400000  -> end 58061824
    char* ws = (char*)d_ws;
    float*          dinv     = (float*)ws;
    float*          stats    = (float*)(ws + 200704);
    int*            bcount   = (int*)(ws + 202752);
    int*            bstart   = (int*)(ws + 206848);
    int*            bcursor  = (int*)(ws + 210944);
    int*            rowstart = (int*)(ws + 261120);
    int*            pairs    = (int*)(ws + 461824);
    unsigned short* xh       = (unsigned short*)(ws + 6861824);
    float*          aggx     = (float*)(ws + 13261824);
    float*          agg1     = (float*)(ws + 26061824);
    unsigned short* h2h      = (unsigned short*)(ws + 51661824);

    const int nblk_cast  = (N_NODES * C1 / 4 + 255) / 256;   // 3125
    const int nblk_rows  = (N_NODES + 31) / 32;
    const int nblk_scat  = (E + STILE - 1) / STILE;          // 391
    const int nblk_pull  = (N_NODES + 3) / 4;

    k_zero_cast<<<nblk_cast, 256, 0, stream>>>(x, xh, bcount, stats);
    k_hist<<<256, 256, 0, stream>>>(dst, E, bcount);
    k_scanb<<<1, 1024, 0, stream>>>(bcount, bstart, bcursor);
    k_scatterc<<<nblk_scat, 256, 0, stream>>>(src, dst, E, bcursor, pairs);
    k_refine<<<NBUCK, 256, 0, stream>>>(bstart, bcount, rowstart, dinv, pairs);

    k_pullx<<<nblk_pull, 256, 0, stream>>>(rowstart, pairs, x, xh, dinv, aggx);
    k_gemm1b<<<nblk_rows, 256, 0, stream>>>(aggx, W1, b1, agg1);

    k_stats<<<256, 256, 0, stream>>>(agg1, stats);
    k_bnparam<<<1, 128, 0, stream>>>(gamma, beta, stats);

    k_gemm2<<<nblk_rows, 256, 0, stream>>>(agg1, W2, stats, h2h);
    k_pull2<<<nblk_pull, 256, 0, stream>>>(rowstart, pairs, h2h, dinv, b2, out);
}